// Round 5
// baseline (434.146 us; speedup 1.0000x reference)
//
#include <hip/hip_runtime.h>
#include <hip/hip_bf16.h>

// R4 post-mortem: reg-dbuf neutral (hides 78 of ~600cyc). New model: weight
// re-fetch traffic (2054 blocks x 410KB = 842MB) served from L3 because obs
// streaming evicts the 2.4MB weight set from the 4MB per-XCD L2.
// R5: (a) 128-row blocks (8 waves x 128rows x 32cols) halve weight traffic,
// (b) nontemporal loads on all read-once streams keep weights L2-resident,
// (c) route_count folded into prep launch.

#define NB 65536
#define ROWS 128
#define XSTR 300   // 288 data + 12 pad shorts; 150 dwords, 150%32=22 -> 16 rows hit 16 distinct banks
#define HSTR 268   // 256 data + 12 pad shorts; 134 dwords, 134%32=6  -> 16 rows hit 16 distinct banks

typedef __attribute__((ext_vector_type(8))) short short8;
typedef __attribute__((ext_vector_type(4))) short short4v;
typedef __attribute__((ext_vector_type(4))) float f32x4;

__device__ __forceinline__ float bf2f(unsigned short u){
  union { unsigned int i; float f; } x; x.i = ((unsigned int)u) << 16; return x.f;
}
__device__ __forceinline__ unsigned short f2bf(float f){
  unsigned int x = __float_as_uint(f);
  x += 0x7fffu + ((x >> 16) & 1u);   // RNE
  return (unsigned short)(x >> 16);
}

struct KParams {
  const void* obs;
  const void* act;
  const unsigned short* w1t[2];
  const unsigned short* w2t[2];
  const unsigned short* w3t[2];
  const void* b1[2];
  const void* b2[2];
  const void* b3[2];
  const void* w4[2];
  const void* b4[2];
  const int* counts;
  const int* perm;
  const int* flag;
  void* out;
};

// ---- dtype sniff ----
__global__ void sniff_kernel(const void* obs, int* flag){
  int lane = threadIdx.x;
  unsigned short u = ((const unsigned short*)obs)[lane * 2];
  int e = (u >> 7) & 0xFF;
  int ok = (e >= 110 && e <= 132) ? 1 : 0;
  unsigned long long m = __ballot(ok);
  if (lane == 0) flag[0] = (__popcll(m) >= 32) ? 1 : 0;
}

__device__ __forceinline__ float ldval(const void* p, int idx, int isbf16){
  return isbf16 ? bf2f(((const unsigned short*)p)[idx]) : ((const float*)p)[idx];
}
// nontemporal scalar read of element idx (streaming, keep out of L2)
__device__ __forceinline__ float ldval_nt(const void* p, int idx, int isbf16){
  if (isbf16) return bf2f(__builtin_nontemporal_load((const unsigned short*)p + idx));
  return __builtin_nontemporal_load((const float*)p + idx);
}

// ---- routing task: exact input precision ----
__device__ __forceinline__ int task_of(const void* obs, int b, int isbf16){
  float v0, v1, v2;
  if (isbf16) {
    short4v u = __builtin_nontemporal_load((const short4v*)((const unsigned short*)obs + b * 256 + 252));
    v0 = bf2f((unsigned short)u[1]); v1 = bf2f((unsigned short)u[2]); v2 = bf2f((unsigned short)u[3]);
  } else {
    f32x4 u = __builtin_nontemporal_load((const f32x4*)((const float*)obs + b * 256 + 252));
    v0 = u[1]; v1 = u[2]; v2 = u[3];
  }
  int t = 0; float m = v0;
  if (v1 > m) { m = v1; t = 1; }   // strict > => first-occurrence argmax (jnp)
  if (v2 > m) { t = 2; }
  return t;
}

// ---- merged weight-prep (blocks 0..4799) + route-count (blocks 4800..5055) ----
__global__ void prep_count(const void* q1W1, const void* q1W2, const void* q1W3,
                           const void* q2W1, const void* q2W2, const void* q2W3,
                           const int* flag, unsigned short* out,
                           const void* obs, int* counts, unsigned char* tasks){
  int isbf16 = flag[0];
  if (blockIdx.x >= 4800) {            // ---- count role ----
    __shared__ int h[3];
    int tid = threadIdx.x;
    if (tid < 3) h[tid] = 0;
    __syncthreads();
    int b = (blockIdx.x - 4800) * 256 + tid;
    int t = task_of(obs, b, isbf16);
    tasks[b] = (unsigned char)t;
    atomicAdd(&h[t], 1);
    __syncthreads();
    if (tid < 3) atomicAdd(&counts[tid], h[tid]);
    return;
  }
  // ---- prep role: coalesced nt reads, scattered writes ----
  int idx = blockIdx.x * 256 + threadIdx.x;
  int net = idx / 614400;
  idx -= net * 614400;
  const void* W1 = net ? q2W1 : q1W1;
  const void* W2 = net ? q2W2 : q1W2;
  const void* W3 = net ? q2W3 : q1W3;
  unsigned short* o = out + net * 614400;
  if (idx < 202752) {                 // W1 copy: src [t][k][n], idx=(t*264+k)*256+n
    int n = idx & 255;
    int tk = idx >> 8;
    int t = tk / 264, k = tk - t * 264;
    o[t * 73728 + n * 288 + k] = f2bf(ldval_nt(W1, idx, isbf16));
  } else if (idx < 221184) {          // W1 K-pad zero (k=264..287)
    int j = idx - 202752;
    int t = j / 6144; int rem = j - t * 6144;
    int n = rem / 24; int k = 264 + (rem - n * 24);
    o[t * 73728 + n * 288 + k] = 0;
  } else if (idx < 417792) {          // W2: j = t*65536 + k*256 + n
    int j = idx - 221184;
    int n = j & 255; int k = (j >> 8) & 255; int t = j >> 16;
    o[221184 + t * 65536 + n * 256 + k] = f2bf(ldval_nt(W2, j, isbf16));
  } else {                            // W3
    int j = idx - 417792;
    int n = j & 255; int k = (j >> 8) & 255; int t = j >> 16;
    o[417792 + t * 65536 + n * 256 + k] = f2bf(ldval_nt(W3, j, isbf16));
  }
}

__global__ void route_scatter(const unsigned char* __restrict__ tasks,
                              const int* counts, int* cursors, int* perm){
  __shared__ int h[3], base[3];
  int tid = threadIdx.x;
  if (tid < 3) h[tid] = 0;
  __syncthreads();
  int b = blockIdx.x * 256 + tid;
  int t = tasks[b];
  int r = atomicAdd(&h[t], 1);
  __syncthreads();
  if (tid < 3) {
    int c0 = counts[0], c1 = counts[1];
    int segoff = (tid == 0) ? 0 : (tid == 1) ? ((c0 + 127) & ~127)
                                             : ((c0 + 127) & ~127) + ((c1 + 127) & ~127);
    base[tid] = segoff + atomicAdd(&cursors[tid], h[tid]);
  }
  __syncthreads();
  perm[base[t] + r] = b;
}

// ---- fused 4-layer routed MLP: 128-row task-uniform tile, 512 thr / 8 waves,
// wave = 128 rows x 32 cols ----
__global__ __launch_bounds__(512, 2) void fused_kernel(KParams p){
  __shared__ unsigned short X[ROWS * XSTR];   // 76,800 B ; reused as HB after layer 1
  __shared__ unsigned short HA[ROWS * HSTR];  // 68,608 B  (total 145,408 <= 160K)
  unsigned short* HB = X;

  int tid = threadIdx.x;
  int net = blockIdx.y;
  int p0  = blockIdx.x * ROWS;
  int isbf16 = p.flag[0];
  int c0 = p.counts[0], c1 = p.counts[1];
  int off1 = (c0 + 127) & ~127;
  int off2 = off1 + ((c1 + 127) & ~127);
  int task = (p0 >= off2) ? 2 : ((p0 >= off1) ? 1 : 0);

  // stage X: 4 threads/row; chunks c = seg+4j cover 0..35 (33 data + 3 K-pad)
  {
    int srow = tid >> 2, seg = tid & 3;
    int r = p.perm[p0 + srow];
    #pragma unroll
    for (int j = 0; j < 9; ++j) {
      int c = seg + 4 * j;
      short8 sv = {0,0,0,0,0,0,0,0};
      if (r >= 0 && c < 33) {
        if (isbf16) {
          const unsigned short* src = (c < 32) ? ((const unsigned short*)p.obs + r * 256 + c * 8)
                                               : ((const unsigned short*)p.act + r * 8);
          sv = __builtin_nontemporal_load((const short8*)src);
        } else {
          const float* src = (c < 32) ? ((const float*)p.obs + r * 256 + c * 8)
                                      : ((const float*)p.act + r * 8);
          f32x4 a = __builtin_nontemporal_load((const f32x4*)src);
          f32x4 b = __builtin_nontemporal_load((const f32x4*)(src + 4));
          #pragma unroll
          for (int q = 0; q < 4; q++) { sv[q] = (short)f2bf(a[q]); sv[4 + q] = (short)f2bf(b[q]); }
        }
      }
      *(short8*)(X + srow * XSTR + c * 8) = sv;
    }
  }
  __syncthreads();

  int wave = tid >> 6, lane = tid & 63, quad = lane >> 4, l16 = lane & 15;
  int nbase = wave * 32;   // each wave owns 32 output cols, all 128 rows

  auto run_layer = [&](const unsigned short* lin, int lstride,
                       const unsigned short* wt, int K,
                       const void* bias, unsigned short* lout){
    f32x4 acc[8][2];
    f32x4 zz = {0.f, 0.f, 0.f, 0.f};
    #pragma unroll
    for (int mt = 0; mt < 8; mt++)
      #pragma unroll
      for (int nt = 0; nt < 2; nt++) acc[mt][nt] = zz;
    const int kc = K >> 5;
    short8 bfr[2][2];
    {   // prologue: chunk 0 B-frags (weights, L2-hot)
      int ko = quad * 8;
      #pragma unroll
      for (int nt = 0; nt < 2; nt++)
        bfr[0][nt] = *(const short8*)(wt + (nbase + nt * 16 + l16) * K + ko);
    }
    for (int kb = 0; kb < kc; ++kb) {
      int cur = kb & 1, nxt = cur ^ 1;
      if (kb + 1 < kc) {   // prefetch next chunk's B-frags
        int ko = ((kb + 1) << 5) + quad * 8;
        #pragma unroll
        for (int nt = 0; nt < 2; nt++)
          bfr[nxt][nt] = *(const short8*)(wt + (nbase + nt * 16 + l16) * K + ko);
      }
      short8 afr[8];
      int ko = (kb << 5) + quad * 8;
      #pragma unroll
      for (int mt = 0; mt < 8; mt++)
        afr[mt] = *(const short8*)(lin + (mt * 16 + l16) * lstride + ko);
      #pragma unroll
      for (int mt = 0; mt < 8; mt++)
        #pragma unroll
        for (int nt = 0; nt < 2; nt++)
          acc[mt][nt] = __builtin_amdgcn_mfma_f32_16x16x32_bf16(afr[mt], bfr[cur][nt], acc[mt][nt], 0, 0, 0);
    }
    float bv[2];
    #pragma unroll
    for (int nt = 0; nt < 2; nt++) bv[nt] = ldval(bias, nbase + nt * 16 + l16, isbf16);
    #pragma unroll
    for (int mt = 0; mt < 8; mt++)
      #pragma unroll
      for (int nt = 0; nt < 2; nt++) {
        f32x4 a = acc[mt][nt];
        #pragma unroll
        for (int r = 0; r < 4; r++) {
          float v = fmaxf(a[r] + bv[nt], 0.f);   // C/D: col=lane&15, row=quad*4+r
          lout[(mt * 16 + quad * 4 + r) * HSTR + nbase + nt * 16 + l16] = f2bf(v);
        }
      }
    __syncthreads();
  };

  run_layer(X,  XSTR, p.w1t[net] + task * 73728, 288, (const char*)p.b1[net] + task * 256 * (isbf16 ? 2 : 4), HA);
  run_layer(HA, HSTR, p.w2t[net] + task * 65536, 256, (const char*)p.b2[net] + task * 256 * (isbf16 ? 2 : 4), HB);
  run_layer(HB, HSTR, p.w3t[net] + task * 65536, 256, (const char*)p.b3[net] + task * 256 * (isbf16 ? 2 : 4), HA);

  // layer 4: y = h3 . w4 + b4  (4 threads per row, shuffle-combine) — 512 thr = 128 rows
  int row = tid >> 2, seg = tid & 3;
  float s = 0.f;
  #pragma unroll
  for (int kk = 0; kk < 64; kk += 8) {
    short8 hv = *(const short8*)(HA + row * HSTR + seg * 64 + kk);
    float wv[8];
    if (isbf16) {
      const unsigned short* w4p = (const unsigned short*)p.w4[net] + task * 256 + seg * 64 + kk;
      short8 t = *(const short8*)w4p;
      #pragma unroll
      for (int j = 0; j < 8; j++) wv[j] = bf2f((unsigned short)t[j]);
    } else {
      const float* w4p = (const float*)p.w4[net] + task * 256 + seg * 64 + kk;
      f32x4 a = *(const f32x4*)w4p;
      f32x4 b = *(const f32x4*)(w4p + 4);
      #pragma unroll
      for (int j = 0; j < 4; j++) { wv[j] = a[j]; wv[4 + j] = b[j]; }
    }
    #pragma unroll
    for (int j = 0; j < 8; j++)
      s += bf2f((unsigned short)hv[j]) * wv[j];
  }
  s += __shfl_xor(s, 1);
  s += __shfl_xor(s, 2);
  if (seg == 0) {
    int r = p.perm[p0 + row];
    if (r >= 0) {
      float y = s + ldval(p.b4[net], task, isbf16);
      if (isbf16) __builtin_nontemporal_store(f2bf(y), (unsigned short*)p.out + net * NB + r);
      else        __builtin_nontemporal_store(y, (float*)p.out + net * NB + r);
    }
  }
}

extern "C" void kernel_launch(void* const* d_in, const int* in_sizes, int n_in,
                              void* d_out, int out_size, void* d_ws, size_t ws_size,
                              hipStream_t stream) {
  char* ws = (char*)d_ws;
  int* counts  = (int*)ws;                   // 3 ints @0
  int* cursors = (int*)(ws + 16);            // 3 ints @16
  int* flag    = (int*)(ws + 48);            // 1 int  @48
  int* perm    = (int*)(ws + 64);            // 66048 ints (516 tiles * 128)
  unsigned char* tasks = (unsigned char*)(ws + 264256);  // 65536 bytes
  unsigned short* wts  = (unsigned short*)(ws + 329856); // 2 * 614400 bf16

  hipMemsetAsync(ws, 0, 64, stream);                 // counts + cursors + flag
  hipMemsetAsync(perm, 0xFF, 66048 * 4, stream);     // perm = -1 (pad sentinel)

  const void* obs = d_in[0];
  const void* act = d_in[1];

  sniff_kernel<<<1, 64, 0, stream>>>(obs, flag);
  prep_count<<<5056, 256, 0, stream>>>(d_in[2], d_in[4], d_in[6],
                                       d_in[10], d_in[12], d_in[14],
                                       flag, wts, obs, counts, tasks);
  route_scatter<<<256, 256, 0, stream>>>(tasks, counts, cursors, perm);

  KParams kp;
  kp.obs = obs; kp.act = act;
  for (int q = 0; q < 2; q++) {
    int base = 2 + q * 8;
    kp.b1[q] = d_in[base + 1];
    kp.b2[q] = d_in[base + 3];
    kp.b3[q] = d_in[base + 5];
    kp.w4[q] = d_in[base + 6];
    kp.b4[q] = d_in[base + 7];
    kp.w1t[q] = wts + q * 614400;
    kp.w2t[q] = wts + q * 614400 + 221184;
    kp.w3t[q] = wts + q * 614400 + 417792;
  }
  kp.counts = counts; kp.perm = perm; kp.flag = flag;
  kp.out = d_out;

  fused_kernel<<<dim3(516, 2), 512, 0, stream>>>(kp);
}

// Round 6
// 277.508 us; speedup vs baseline: 1.5644x; 1.5644x over previous
//
#include <hip/hip_runtime.h>
#include <hip/hip_bf16.h>

// R5 post-mortem (FAILED, 164->305us fused): 128-row tile put LDS at 145KB ->
// 1 block/CU (correlated barriers/stalls, no co-resident overlap) AND strides
// 300/268 shorts broke 16B alignment (b128 -> b64 splits). Weight-traffic
// theory disproven (halving traffic didn't help): we are LATENCY-bound.
// R6: revert to R4 64-row/2-blocks-per-CU structure; template-unroll K-loop
// and preload ALL per-layer B-frags (one pipeline fill per layer instead of
// per-chunk stalls); inline dtype sniff per block (kills launch-chain dep).

#define NB 65536
#define XSTR 296   // 592B row stride: %16==0 (b128 ok), dword stride 148%32=20 -> 2-way (free)
#define HSTR 264   // 528B row stride: %16==0, dword stride 132%32=4 -> 2-way (free)

typedef __attribute__((ext_vector_type(8))) short short8;
typedef __attribute__((ext_vector_type(4))) short short4v;
typedef __attribute__((ext_vector_type(4))) float f32x4;

__device__ __forceinline__ float bf2f(unsigned short u){
  union { unsigned int i; float f; } x; x.i = ((unsigned int)u) << 16; return x.f;
}
__device__ __forceinline__ unsigned short f2bf(float f){
  unsigned int x = __float_as_uint(f);
  x += 0x7fffu + ((x >> 16) & 1u);   // RNE
  return (unsigned short)(x >> 16);
}
__device__ __forceinline__ float ldval(const void* p, int idx, int isbf16){
  return isbf16 ? bf2f(((const unsigned short*)p)[idx]) : ((const float*)p)[idx];
}

// wave-0 dtype sniff (low short of dwords: bf16 data -> N(0,1) exponents;
// fp32 data -> random mantissa bits). Call with full block, returns via LDS.
__device__ __forceinline__ int block_sniff(const void* obs, int tid, int* sflag){
  if (tid < 64) {
    unsigned short u = ((const unsigned short*)obs)[tid * 2];
    int e = (u >> 7) & 0xFF;
    unsigned long long m = __ballot(e >= 110 && e <= 132);
    if (tid == 0) *sflag = (__popcll(m) >= 32) ? 1 : 0;
  }
  __syncthreads();
  return *sflag;
}

struct KParams {
  const void* obs;
  const void* act;
  const unsigned short* w1t[2];
  const unsigned short* w2t[2];
  const unsigned short* w3t[2];
  const void* b1[2];
  const void* b2[2];
  const void* b3[2];
  const void* w4[2];
  const void* b4[2];
  const int* counts;
  const int* perm;
  void* out;
};

// ---- weight prep: COALESCED vectorized writes (8 shorts/thread), gather
// reads (src 2.4-4.8MB, L2-cached, each line reused ~256x across n) ----
__global__ void prep_kernel(const void* q1W1, const void* q1W2, const void* q1W3,
                            const void* q2W1, const void* q2W2, const void* q2W3,
                            const void* obs, unsigned short* out){
  __shared__ int sflag;
  int tid = threadIdx.x;
  int isbf16 = block_sniff(obs, tid, &sflag);
  int gid8 = (blockIdx.x * 256 + tid) * 8;
  int net = gid8 / 614400;
  int idx = gid8 - net * 614400;
  const void* W1 = net ? q2W1 : q1W1;
  const void* W2 = net ? q2W2 : q1W2;
  const void* W3 = net ? q2W3 : q1W3;
  short8 sv;
  if (idx < 221184) {                 // W1t [3][256][288]: row len 288 %8==0
    int t = idx / 73728; int rem = idx - t * 73728;
    int n = rem / 288;   int k = rem - n * 288;
    #pragma unroll
    for (int j = 0; j < 8; j++) {
      int kk = k + j;
      sv[j] = (kk < 264) ? (short)f2bf(ldval(W1, (t * 264 + kk) * 256 + n, isbf16)) : (short)0;
    }
  } else if (idx < 417792) {          // W2t [3][256][256]
    int j0 = idx - 221184;
    int t = j0 >> 16; int n = (j0 >> 8) & 255; int k = j0 & 255;
    #pragma unroll
    for (int j = 0; j < 8; j++)
      sv[j] = (short)f2bf(ldval(W2, t * 65536 + (k + j) * 256 + n, isbf16));
  } else {                            // W3t
    int j0 = idx - 417792;
    int t = j0 >> 16; int n = (j0 >> 8) & 255; int k = j0 & 255;
    #pragma unroll
    for (int j = 0; j < 8; j++)
      sv[j] = (short)f2bf(ldval(W3, t * 65536 + (k + j) * 256 + n, isbf16));
  }
  *(short8*)(out + net * 614400 + idx) = sv;
}

// ---- routing: exact input precision, per-block LDS histogram ----
__device__ __forceinline__ int task_of(const void* obs, int b, int isbf16){
  float v0, v1, v2;
  if (isbf16) {
    short4v u = *(const short4v*)((const unsigned short*)obs + b * 256 + 252);
    v0 = bf2f((unsigned short)u[1]); v1 = bf2f((unsigned short)u[2]); v2 = bf2f((unsigned short)u[3]);
  } else {
    f32x4 u = *(const f32x4*)((const float*)obs + b * 256 + 252);
    v0 = u[1]; v1 = u[2]; v2 = u[3];
  }
  int t = 0; float m = v0;
  if (v1 > m) { m = v1; t = 1; }   // strict > => first-occurrence argmax (jnp)
  if (v2 > m) { t = 2; }
  return t;
}

__global__ void route_count(const void* __restrict__ obs, int* counts, unsigned char* tasks){
  __shared__ int sflag;
  __shared__ int h[3];
  int tid = threadIdx.x;
  int isbf16 = block_sniff(obs, tid, &sflag);
  if (tid < 3) h[tid] = 0;
  __syncthreads();
  int b = blockIdx.x * 256 + tid;
  int t = task_of(obs, b, isbf16);
  tasks[b] = (unsigned char)t;
  atomicAdd(&h[t], 1);
  __syncthreads();
  if (tid < 3) atomicAdd(&counts[tid], h[tid]);
}

__global__ void route_scatter(const unsigned char* __restrict__ tasks,
                              const int* counts, int* cursors, int* perm){
  __shared__ int h[3], base[3];
  int tid = threadIdx.x;
  if (tid < 3) h[tid] = 0;
  __syncthreads();
  int b = blockIdx.x * 256 + tid;
  int t = tasks[b];
  int r = atomicAdd(&h[t], 1);
  __syncthreads();
  if (tid < 3) {
    int c0 = counts[0], c1 = counts[1];
    int segoff = (tid == 0) ? 0 : (tid == 1) ? ((c0 + 63) & ~63)
                                             : ((c0 + 63) & ~63) + ((c1 + 63) & ~63);
    base[tid] = segoff + atomicAdd(&cursors[tid], h[tid]);
  }
  __syncthreads();
  perm[base[t] + r] = b;
}

// ---- one layer, fully unrolled: preload ALL B-frags (KC*4 independent global
// loads -> one pipeline fill per layer), then per-chunk LDS A reads + MFMA ----
template<int KC>
__device__ __forceinline__ void run_layer(const unsigned short* __restrict__ lin, int lstride,
                                          const unsigned short* __restrict__ wt,
                                          const void* bias, unsigned short* lout,
                                          int isbf16, int quad, int l16, int nbase){
  constexpr int K = KC * 32;
  short8 bfr[KC][4];
  #pragma unroll
  for (int kb = 0; kb < KC; ++kb) {
    int ko = kb * 32 + quad * 8;
    #pragma unroll
    for (int nt = 0; nt < 4; nt++)
      bfr[kb][nt] = *(const short8*)(wt + (nbase + nt * 16 + l16) * K + ko);
  }
  f32x4 acc[4][4] = {};
  #pragma unroll
  for (int kb = 0; kb < KC; ++kb) {
    short8 afr[4];
    int ko = kb * 32 + quad * 8;
    #pragma unroll
    for (int mt = 0; mt < 4; mt++)
      afr[mt] = *(const short8*)(lin + (mt * 16 + l16) * lstride + ko);
    #pragma unroll
    for (int mt = 0; mt < 4; mt++)
      #pragma unroll
      for (int nt = 0; nt < 4; nt++)
        acc[mt][nt] = __builtin_amdgcn_mfma_f32_16x16x32_bf16(afr[mt], bfr[kb][nt], acc[mt][nt], 0, 0, 0);
  }
  float bv[4];
  #pragma unroll
  for (int nt = 0; nt < 4; nt++) bv[nt] = ldval(bias, nbase + nt * 16 + l16, isbf16);
  #pragma unroll
  for (int mt = 0; mt < 4; mt++)
    #pragma unroll
    for (int nt = 0; nt < 4; nt++) {
      f32x4 a = acc[mt][nt];
      #pragma unroll
      for (int r = 0; r < 4; r++) {
        float v = fmaxf(a[r] + bv[nt], 0.f);   // C/D: col=lane&15, row=quad*4+r
        lout[(mt * 16 + quad * 4 + r) * HSTR + nbase + nt * 16 + l16] = f2bf(v);
      }
    }
  __syncthreads();
}

// ---- fused 4-layer routed MLP, 64-row task-uniform tile, 256 thr / 4 waves,
// wave = 64 rows x 64 cols; LDS 71.7KB -> 2 blocks/CU ----
__global__ __launch_bounds__(256, 2) void fused_kernel(KParams p){
  __shared__ unsigned short X[64 * XSTR];   // 37,888 B ; reused as HB after layer 1
  __shared__ unsigned short HA[64 * HSTR];  // 33,792 B
  __shared__ int sflag;
  unsigned short* HB = X;

  int tid = threadIdx.x;
  int net = blockIdx.y;
  int p0  = blockIdx.x * 64;
  int isbf16 = block_sniff(p.obs, tid, &sflag);
  int c0 = p.counts[0], c1 = p.counts[1];
  int off1 = (c0 + 63) & ~63;
  int off2 = off1 + ((c1 + 63) & ~63);
  int task = (p0 >= off2) ? 2 : ((p0 >= off1) ? 1 : 0);

  // stage X: 4 threads/row; 1 perm load then independent global loads
  {
    int srow = tid >> 2, seg = tid & 3;
    int r = p.perm[p0 + srow];
    #pragma unroll
    for (int j = 0; j < 9; ++j) {
      int c = seg + 4 * j;
      if (c < 33) {
        short8 sv = {0,0,0,0,0,0,0,0};
        if (r >= 0) {
          if (isbf16) {
            const unsigned short* src = (c < 32) ? ((const unsigned short*)p.obs + r * 256 + c * 8)
                                                 : ((const unsigned short*)p.act + r * 8);
            sv = *(const short8*)src;
          } else {
            const float* src = (c < 32) ? ((const float*)p.obs + r * 256 + c * 8)
                                        : ((const float*)p.act + r * 8);
            f32x4 a = *(const f32x4*)src;
            f32x4 b = *(const f32x4*)(src + 4);
            #pragma unroll
            for (int q = 0; q < 4; q++) { sv[q] = (short)f2bf(a[q]); sv[4 + q] = (short)f2bf(b[q]); }
          }
        }
        *(short8*)(X + srow * XSTR + c * 8) = sv;
      }
    }
    if (seg < 3) {                       // zero K-pad cols 264..287 (chunks 33..35)
      short8 z = {0,0,0,0,0,0,0,0};
      *(short8*)(X + srow * XSTR + (33 + seg) * 8) = z;
    }
  }
  __syncthreads();

  int wave = tid >> 6, lane = tid & 63, quad = lane >> 4, l16 = lane & 15;
  int nbase = wave * 64;   // each wave owns 64 output cols

  int bsz = isbf16 ? 2 : 4;
  run_layer<9>(X,  XSTR, p.w1t[net] + task * 73728, (const char*)p.b1[net] + task * 256 * bsz, HA, isbf16, quad, l16, nbase);
  run_layer<8>(HA, HSTR, p.w2t[net] + task * 65536, (const char*)p.b2[net] + task * 256 * bsz, HB, isbf16, quad, l16, nbase);
  run_layer<8>(HB, HSTR, p.w3t[net] + task * 65536, (const char*)p.b3[net] + task * 256 * bsz, HA, isbf16, quad, l16, nbase);

  // layer 4: y = h3 . w4 + b4  (4 threads per row, shuffle-combine)
  int row = tid >> 2, seg = tid & 3;
  float s = 0.f;
  #pragma unroll
  for (int kk = 0; kk < 64; kk += 8) {
    short8 hv = *(const short8*)(HA + row * HSTR + seg * 64 + kk);
    float wv[8];
    if (isbf16) {
      const unsigned short* w4p = (const unsigned short*)p.w4[net] + task * 256 + seg * 64 + kk;
      short8 t = *(const short8*)w4p;
      #pragma unroll
      for (int j = 0; j < 8; j++) wv[j] = bf2f((unsigned short)t[j]);
    } else {
      const float* w4p = (const float*)p.w4[net] + task * 256 + seg * 64 + kk;
      f32x4 a = *(const f32x4*)w4p;
      f32x4 b = *(const f32x4*)(w4p + 4);
      #pragma unroll
      for (int j = 0; j < 4; j++) { wv[j] = a[j]; wv[4 + j] = b[j]; }
    }
    #pragma unroll
    for (int j = 0; j < 8; j++)
      s += bf2f((unsigned short)hv[j]) * wv[j];
  }
  s += __shfl_xor(s, 1);
  s += __shfl_xor(s, 2);
  if (seg == 0) {
    int r = p.perm[p0 + row];
    if (r >= 0) {
      float y = s + ldval(p.b4[net], task, isbf16);
      if (isbf16) ((unsigned short*)p.out)[net * NB + r] = f2bf(y);
      else        ((float*)p.out)[net * NB + r] = y;
    }
  }
}

extern "C" void kernel_launch(void* const* d_in, const int* in_sizes, int n_in,
                              void* d_out, int out_size, void* d_ws, size_t ws_size,
                              hipStream_t stream) {
  char* ws = (char*)d_ws;
  int* counts  = (int*)ws;                   // 3 ints @0
  int* cursors = (int*)(ws + 16);            // 3 ints @16
  int* perm    = (int*)(ws + 64);            // 65728 ints (1027 tiles * 64)
  unsigned char* tasks = (unsigned char*)(ws + 263168);  // 65536 bytes
  unsigned short* wts  = (unsigned short*)(ws + 328704); // 2 * 614400 bf16

  hipMemsetAsync(ws, 0, 64, stream);                 // counts + cursors
  hipMemsetAsync(perm, 0xFF, 65728 * 4, stream);     // perm = -1 (pad sentinel)

  const void* obs = d_in[0];
  const void* act = d_in[1];

  prep_kernel<<<600, 256, 0, stream>>>(d_in[2], d_in[4], d_in[6],
                                       d_in[10], d_in[12], d_in[14], obs, wts);
  route_count<<<256, 256, 0, stream>>>(obs, counts, tasks);
  route_scatter<<<256, 256, 0, stream>>>(tasks, counts, cursors, perm);

  KParams kp;
  kp.obs = obs; kp.act = act;
  for (int q = 0; q < 2; q++) {
    int base = 2 + q * 8;
    kp.b1[q] = d_in[base + 1];
    kp.b2[q] = d_in[base + 3];
    kp.b3[q] = d_in[base + 5];
    kp.w4[q] = d_in[base + 6];
    kp.b4[q] = d_in[base + 7];
    kp.w1t[q] = wts + q * 614400;
    kp.w2t[q] = wts + q * 614400 + 221184;
    kp.w3t[q] = wts + q * 614400 + 417792;
  }
  kp.counts = counts; kp.perm = perm;
  kp.out = d_out;

  fused_kernel<<<dim3(1027, 2), 256, 0, stream>>>(kp);
}

// Round 7
// 223.734 us; speedup vs baseline: 1.9405x; 1.2403x over previous
//
#include <hip/hip_runtime.h>
#include <hip/hip_bf16.h>

// R6 post-mortem: preload defeated by scheduler (VGPR stayed 88); ~163us is a
// latency-chain invariant at 8 waves/CU. R7 levers:
//  (1) 512-thr blocks: 8 waves x (64 rows x 32 cols), same 72KB LDS -> still
//      2 blocks/CU but 16 waves/CU (launch_bounds(512,4) caps VGPR 128).
//  (2) weights pre-swizzled into B-frag order: each B-load = contiguous 1KB.
//  (3) prefix: 3 dispatches, 0 memsets (hist stores overwrite poison; scatter
//      recomputes prefix; fused validity is arithmetic, no sentinel).

#define NB 65536
#define XSTR 296   // 592B row: %16==0, dword stride 148%32=20 -> 2-way (free)
#define HSTR 264   // 528B row: %16==0, dword stride 132%32=4  -> 2-way (free)

typedef __attribute__((ext_vector_type(8))) short short8;
typedef __attribute__((ext_vector_type(4))) short short4v;
typedef __attribute__((ext_vector_type(4))) float f32x4;

__device__ __forceinline__ float bf2f(unsigned short u){
  union { unsigned int i; float f; } x; x.i = ((unsigned int)u) << 16; return x.f;
}
__device__ __forceinline__ unsigned short f2bf(float f){
  unsigned int x = __float_as_uint(f);
  x += 0x7fffu + ((x >> 16) & 1u);   // RNE
  return (unsigned short)(x >> 16);
}
__device__ __forceinline__ float ldval(const void* p, int idx, int isbf16){
  return isbf16 ? bf2f(((const unsigned short*)p)[idx]) : ((const float*)p)[idx];
}

// wave-0 dtype sniff: low short of dword groups. bf16 -> N(0,1) exponents;
// fp32 -> random mantissa bits (~9% in range). Returns via LDS flag.
__device__ __forceinline__ int block_sniff(const void* obs, int tid, int* sflag){
  if (tid < 64) {
    unsigned short u = ((const unsigned short*)obs)[tid * 2];
    int e = (u >> 7) & 0xFF;
    unsigned long long m = __ballot(e >= 110 && e <= 132);
    if (tid == 0) *sflag = (__popcll(m) >= 32) ? 1 : 0;
  }
  __syncthreads();
  return *sflag;
}

struct KParams {
  const void* obs;
  const void* act;
  const unsigned short* w1t[2];   // swizzled [task][g16][kb9][l16][quad][8]
  const unsigned short* w2t[2];   // swizzled [task][g16][kb8][l16][quad][8]
  const unsigned short* w3t[2];
  const void* b1[2];
  const void* b2[2];
  const void* b3[2];
  const void* w4[2];
  const void* b4[2];
  const int* counts;
  const int* perm;
  void* out;
};

// ---- routing task: exact input precision ----
__device__ __forceinline__ int task_of(const void* obs, int b, int isbf16){
  float v0, v1, v2;
  if (isbf16) {
    short4v u = *(const short4v*)((const unsigned short*)obs + b * 256 + 252);
    v0 = bf2f((unsigned short)u[1]); v1 = bf2f((unsigned short)u[2]); v2 = bf2f((unsigned short)u[3]);
  } else {
    f32x4 u = *(const f32x4*)((const float*)obs + b * 256 + 252);
    v0 = u[1]; v1 = u[2]; v2 = u[3];
  }
  int t = 0; float m = v0;
  if (v1 > m) { m = v1; t = 1; }   // strict > => first-occurrence argmax (jnp)
  if (v2 > m) { t = 2; }
  return t;
}

// ---- K1: blocks 0..599 = weight prep (swizzled B-frag layout, vectorized
// coalesced writes); blocks 600..855 = per-block task histogram (plain stores
// overwrite ws poison -> no memset needed) ----
__global__ void prep_count(const void* q1W1, const void* q1W2, const void* q1W3,
                           const void* q2W1, const void* q2W2, const void* q2W3,
                           const void* obs, unsigned short* out,
                           int* hist, unsigned char* tasks){
  __shared__ int sflag;
  int tid = threadIdx.x;
  int isbf16 = block_sniff(obs, tid, &sflag);
  if (blockIdx.x >= 600) {             // ---- count role ----
    __shared__ int h[3];
    if (tid < 3) h[tid] = 0;
    __syncthreads();
    int blk = blockIdx.x - 600;
    int b = blk * 256 + tid;
    int t = task_of(obs, b, isbf16);
    tasks[b] = (unsigned char)t;
    atomicAdd(&h[t], 1);
    __syncthreads();
    if (tid < 3) hist[blk * 3 + tid] = h[tid];   // plain store (overwrites poison)
    return;
  }
  // ---- prep role: thread writes 8 consecutive swizzled shorts ----
  int gid8 = (blockIdx.x * 256 + tid) * 8;
  int net = gid8 / 614400;
  int idx = gid8 - net * 614400;
  const void* W1 = net ? q2W1 : q1W1;
  const void* W2 = net ? q2W2 : q1W2;
  const void* W3 = net ? q2W3 : q1W3;
  short8 sv;
  if (idx < 221184) {                  // W1t: KC=9, per task 16*9*512=73728
    int t = idx / 73728; int i = idx - t * 73728;
    int g = i / 4608;  int r = i - g * 4608;
    int kb = r >> 9;   int q2 = r & 511;
    int l16 = q2 >> 5; int rem = q2 & 31;
    int n = g * 16 + l16;
    int k = kb * 32 + (rem & ~7);      // rem%8==0 for 8-aligned thread base
    #pragma unroll
    for (int j = 0; j < 8; j++) {
      int kk = k + j;
      sv[j] = (kk < 264) ? (short)f2bf(ldval(W1, (t * 264 + kk) * 256 + n, isbf16)) : (short)0;
    }
  } else if (idx < 417792) {           // W2t: KC=8, per task 16*8*512=65536
    int j0 = idx - 221184;
    int t = j0 >> 16; int i = j0 & 65535;
    int g = i >> 12;  int r = i & 4095;
    int kb = r >> 9;  int q2 = r & 511;
    int l16 = q2 >> 5; int rem = q2 & 31;
    int n = g * 16 + l16;
    int k = kb * 32 + (rem & ~7);
    #pragma unroll
    for (int j = 0; j < 8; j++)
      sv[j] = (short)f2bf(ldval(W2, t * 65536 + (k + j) * 256 + n, isbf16));
  } else {                             // W3t
    int j0 = idx - 417792;
    int t = j0 >> 16; int i = j0 & 65535;
    int g = i >> 12;  int r = i & 4095;
    int kb = r >> 9;  int q2 = r & 511;
    int l16 = q2 >> 5; int rem = q2 & 31;
    int n = g * 16 + l16;
    int k = kb * 32 + (rem & ~7);
    #pragma unroll
    for (int j = 0; j < 8; j++)
      sv[j] = (short)f2bf(ldval(W3, t * 65536 + (k + j) * 256 + n, isbf16));
  }
  *(short8*)(out + net * 614400 + idx) = sv;
}

// ---- K2: scatter. Atomic-free cross-block coordination: each block reads all
// 256x3 hists, computes totals + its own prefix. Block 0 publishes counts. ----
__global__ void route_scatter(const unsigned char* __restrict__ tasks,
                              const int* __restrict__ hist,
                              int* counts, int* perm){
  __shared__ int sh[3][256];
  __shared__ int totals[3], pres[3], base[3], zz[3];
  int tid = threadIdx.x;
  int blk = blockIdx.x;
  sh[0][tid] = hist[tid * 3 + 0];
  sh[1][tid] = hist[tid * 3 + 1];
  sh[2][tid] = hist[tid * 3 + 2];
  if (tid < 3) zz[tid] = 0;
  __syncthreads();
  if (tid < 3) {
    int tot = 0, pre = 0;
    for (int b = 0; b < 256; b++) {
      int v = sh[tid][b];
      if (b < blk) pre += v;
      tot += v;
    }
    totals[tid] = tot; pres[tid] = pre;
  }
  __syncthreads();
  if (tid < 3) {
    int off = (tid == 0) ? 0 : (tid == 1) ? ((totals[0] + 63) & ~63)
                                          : ((totals[0] + 63) & ~63) + ((totals[1] + 63) & ~63);
    base[tid] = off + pres[tid];
    if (blk == 0) counts[tid] = totals[tid];
  }
  __syncthreads();
  int b = blk * 256 + tid;
  int t = tasks[b];
  int r = atomicAdd(&zz[t], 1);
  perm[base[t] + r] = b;
}

// ---- one layer: template-unrolled K, per-wave 64 rows x 32 cols ----
template<int KC>
__device__ __forceinline__ void run_layer(const unsigned short* __restrict__ lin, int lstride,
                                          const unsigned short* __restrict__ wt,
                                          const void* bias, unsigned short* lout,
                                          int isbf16, int wave, int quad, int l16, int nbase){
  // swizzled B-frag base for this wave's two 16-col groups
  const unsigned short* wg = wt + (wave * 2) * (KC * 512) + l16 * 32 + quad * 8;
  short8 bfr[KC][2];
  #pragma unroll
  for (int kb = 0; kb < KC; ++kb) {
    bfr[kb][0] = *(const short8*)(wg + kb * 512);
    bfr[kb][1] = *(const short8*)(wg + KC * 512 + kb * 512);
  }
  f32x4 acc[4][2] = {};
  #pragma unroll
  for (int kb = 0; kb < KC; ++kb) {
    short8 afr[4];
    int ko = kb * 32 + quad * 8;
    #pragma unroll
    for (int mt = 0; mt < 4; mt++)
      afr[mt] = *(const short8*)(lin + (mt * 16 + l16) * lstride + ko);
    #pragma unroll
    for (int mt = 0; mt < 4; mt++)
      #pragma unroll
      for (int nt = 0; nt < 2; nt++)
        acc[mt][nt] = __builtin_amdgcn_mfma_f32_16x16x32_bf16(afr[mt], bfr[kb][nt], acc[mt][nt], 0, 0, 0);
  }
  float bv[2];
  #pragma unroll
  for (int nt = 0; nt < 2; nt++) bv[nt] = ldval(bias, nbase + nt * 16 + l16, isbf16);
  #pragma unroll
  for (int mt = 0; mt < 4; mt++)
    #pragma unroll
    for (int nt = 0; nt < 2; nt++) {
      f32x4 a = acc[mt][nt];
      #pragma unroll
      for (int r = 0; r < 4; r++) {
        float v = fmaxf(a[r] + bv[nt], 0.f);   // C/D: col=lane&15, row=quad*4+r
        lout[(mt * 16 + quad * 4 + r) * HSTR + nbase + nt * 16 + l16] = f2bf(v);
      }
    }
  __syncthreads();
}

// ---- fused: 64-row task-uniform tile, 512 thr / 8 waves (16 waves/CU at
// 2 blocks/CU), wave = 64 rows x 32 cols ----
__global__ __launch_bounds__(512, 4) void fused_kernel(KParams p){
  __shared__ unsigned short X[64 * XSTR];   // 37,888 B ; reused as HB after L1
  __shared__ unsigned short HA[64 * HSTR];  // 33,792 B  (total ~70KB -> 2 blk/CU)
  __shared__ int sflag;
  unsigned short* HB = X;

  int tid = threadIdx.x;
  int net = blockIdx.y;
  int p0  = blockIdx.x * 64;
  int isbf16 = block_sniff(p.obs, tid, &sflag);
  int c0 = p.counts[0], c1 = p.counts[1], c2 = p.counts[2];
  int off1 = (c0 + 63) & ~63;
  int off2 = off1 + ((c1 + 63) & ~63);
  int task  = (p0 >= off2) ? 2 : ((p0 >= off1) ? 1 : 0);
  int segend = (task == 0) ? c0 : (task == 1) ? off1 + c1 : off2 + c2;

  // stage X: 8 threads/row; validity is arithmetic (no sentinel in perm)
  {
    int srow = tid >> 3, seg = tid & 7;
    int pos = p0 + srow;
    int r = (pos < segend) ? p.perm[pos] : -1;
    #pragma unroll
    for (int j = 0; j < 5; ++j) {
      int c = seg + 8 * j;
      if (c <= 35) {
        short8 sv = {0,0,0,0,0,0,0,0};
        if (r >= 0 && c < 33) {
          if (isbf16) {
            const unsigned short* src = (c < 32) ? ((const unsigned short*)p.obs + r * 256 + c * 8)
                                                 : ((const unsigned short*)p.act + r * 8);
            sv = *(const short8*)src;
          } else {
            const float* src = (c < 32) ? ((const float*)p.obs + r * 256 + c * 8)
                                        : ((const float*)p.act + r * 8);
            f32x4 a = *(const f32x4*)src;
            f32x4 b = *(const f32x4*)(src + 4);
            #pragma unroll
            for (int q = 0; q < 4; q++) { sv[q] = (short)f2bf(a[q]); sv[4 + q] = (short)f2bf(b[q]); }
          }
        }
        *(short8*)(X + srow * XSTR + c * 8) = sv;
      }
    }
  }
  __syncthreads();

  int wave = tid >> 6, lane = tid & 63, quad = lane >> 4, l16 = lane & 15;
  int nbase = wave * 32;   // each of 8 waves owns 32 output cols

  int bsz = isbf16 ? 2 : 4;
  run_layer<9>(X,  XSTR, p.w1t[net] + task * 73728, (const char*)p.b1[net] + task * 256 * bsz, HA, isbf16, wave, quad, l16, nbase);
  run_layer<8>(HA, HSTR, p.w2t[net] + task * 65536, (const char*)p.b2[net] + task * 256 * bsz, HB, isbf16, wave, quad, l16, nbase);
  run_layer<8>(HB, HSTR, p.w3t[net] + task * 65536, (const char*)p.b3[net] + task * 256 * bsz, HA, isbf16, wave, quad, l16, nbase);

  // layer 4: y = h3 . w4 + b4  (8 threads/row, 3-level shuffle)
  int row = tid >> 3, seg = tid & 7;
  float s = 0.f;
  #pragma unroll
  for (int kk = 0; kk < 32; kk += 8) {
    short8 hv = *(const short8*)(HA + row * HSTR + seg * 32 + kk);
    float wv[8];
    if (isbf16) {
      const unsigned short* w4p = (const unsigned short*)p.w4[net] + task * 256 + seg * 32 + kk;
      short8 t = *(const short8*)w4p;
      #pragma unroll
      for (int j = 0; j < 8; j++) wv[j] = bf2f((unsigned short)t[j]);
    } else {
      const float* w4p = (const float*)p.w4[net] + task * 256 + seg * 32 + kk;
      f32x4 a = *(const f32x4*)w4p;
      f32x4 b = *(const f32x4*)(w4p + 4);
      #pragma unroll
      for (int j = 0; j < 4; j++) { wv[j] = a[j]; wv[4 + j] = b[j]; }
    }
    #pragma unroll
    for (int j = 0; j < 8; j++)
      s += bf2f((unsigned short)hv[j]) * wv[j];
  }
  s += __shfl_xor(s, 1);
  s += __shfl_xor(s, 2);
  s += __shfl_xor(s, 4);
  if (seg == 0) {
    int pos = p0 + row;
    if (pos < segend) {
      int r = p.perm[pos];
      float y = s + ldval(p.b4[net], task, isbf16);
      if (isbf16) ((unsigned short*)p.out)[net * NB + r] = f2bf(y);
      else        ((float*)p.out)[net * NB + r] = y;
    }
  }
}

extern "C" void kernel_launch(void* const* d_in, const int* in_sizes, int n_in,
                              void* d_out, int out_size, void* d_ws, size_t ws_size,
                              hipStream_t stream) {
  char* ws = (char*)d_ws;
  int* counts  = (int*)ws;                                // 3 ints @0 (written by K2)
  int* hist    = (int*)(ws + 64);                         // 256*3 ints (K1 stores)
  unsigned char* tasks = (unsigned char*)(ws + 3200);     // 65536 B (K1 stores)
  int* perm    = (int*)(ws + 68800);                      // 65664 ints (K2 stores)
  unsigned short* wts  = (unsigned short*)(ws + 331520);  // 2*614400 bf16 (K1 stores)

  const void* obs = d_in[0];
  const void* act = d_in[1];

  prep_count<<<856, 256, 0, stream>>>(d_in[2], d_in[4], d_in[6],
                                      d_in[10], d_in[12], d_in[14],
                                      obs, wts, hist, tasks);
  route_scatter<<<256, 256, 0, stream>>>(tasks, hist, counts, perm);

  KParams kp;
  kp.obs = obs; kp.act = act;
  for (int q = 0; q < 2; q++) {
    int base = 2 + q * 8;
    kp.b1[q] = d_in[base + 1];
    kp.b2[q] = d_in[base + 3];
    kp.b3[q] = d_in[base + 5];
    kp.w4[q] = d_in[base + 6];
    kp.b4[q] = d_in[base + 7];
    kp.w1t[q] = wts + q * 614400;
    kp.w2t[q] = wts + q * 614400 + 221184;
    kp.w3t[q] = wts + q * 614400 + 417792;
  }
  kp.counts = counts; kp.perm = perm;
  kp.out = d_out;

  fused_kernel<<<dim3(1026, 2), 512, 0, stream>>>(kp);
}

// Round 8
// 222.013 us; speedup vs baseline: 1.9555x; 1.0078x over previous
//
#include <hip/hip_runtime.h>
#include <hip/hip_bf16.h>

// R7 post-mortem (WIN, 163->111us fused): occupancy 8->16 waves/CU gave 1.47x;
// latency-bound model confirmed. Non-fused ~112us is invariant harness/launch
// overhead (R3-R7 evidence). R8: third co-resident block. 48-row tiles shrink
// LDS to exactly 53,760B (X 28,416 + HA 25,344, sflag aliased into HA) -> 3
// blocks/CU = 24 waves/CU. launch_bounds(512,6) caps VGPR 85. Weight traffic
// +33% (L2-served, latency-bound so acceptable).

#define NB 65536
#define MROWS 48   // row tile (mt=3 x 16)
#define XSTR 296   // 592B row: %16==0, 16B-unit stride 37 (odd) -> 2-way max (free)
#define HSTR 264   // 528B row: %16==0, 16B-unit stride 33 (odd) -> 2-way max (free)

typedef __attribute__((ext_vector_type(8))) short short8;
typedef __attribute__((ext_vector_type(4))) short short4v;
typedef __attribute__((ext_vector_type(4))) float f32x4;

__device__ __forceinline__ float bf2f(unsigned short u){
  union { unsigned int i; float f; } x; x.i = ((unsigned int)u) << 16; return x.f;
}
__device__ __forceinline__ unsigned short f2bf(float f){
  unsigned int x = __float_as_uint(f);
  x += 0x7fffu + ((x >> 16) & 1u);   // RNE
  return (unsigned short)(x >> 16);
}
__device__ __forceinline__ float ldval(const void* p, int idx, int isbf16){
  return isbf16 ? bf2f(((const unsigned short*)p)[idx]) : ((const float*)p)[idx];
}

// wave-0 dtype sniff: low short of dword groups. bf16 -> N(0,1) exponents;
// fp32 -> random mantissa bits (~9% in range). Returns via LDS flag.
__device__ __forceinline__ int block_sniff(const void* obs, int tid, int* sflag){
  if (tid < 64) {
    unsigned short u = ((const unsigned short*)obs)[tid * 2];
    int e = (u >> 7) & 0xFF;
    unsigned long long m = __ballot(e >= 110 && e <= 132);
    if (tid == 0) *sflag = (__popcll(m) >= 32) ? 1 : 0;
  }
  __syncthreads();
  return *sflag;
}

struct KParams {
  const void* obs;
  const void* act;
  const unsigned short* w1t[2];   // swizzled [task][g16][kb9][l16][quad][8]
  const unsigned short* w2t[2];   // swizzled [task][g16][kb8][l16][quad][8]
  const unsigned short* w3t[2];
  const void* b1[2];
  const void* b2[2];
  const void* b3[2];
  const void* w4[2];
  const void* b4[2];
  const int* counts;
  const int* perm;
  void* out;
};

// ---- routing task: exact input precision ----
__device__ __forceinline__ int task_of(const void* obs, int b, int isbf16){
  float v0, v1, v2;
  if (isbf16) {
    short4v u = *(const short4v*)((const unsigned short*)obs + b * 256 + 252);
    v0 = bf2f((unsigned short)u[1]); v1 = bf2f((unsigned short)u[2]); v2 = bf2f((unsigned short)u[3]);
  } else {
    f32x4 u = *(const f32x4*)((const float*)obs + b * 256 + 252);
    v0 = u[1]; v1 = u[2]; v2 = u[3];
  }
  int t = 0; float m = v0;
  if (v1 > m) { m = v1; t = 1; }   // strict > => first-occurrence argmax (jnp)
  if (v2 > m) { t = 2; }
  return t;
}

// ---- K1: blocks 0..599 = weight prep (swizzled B-frag layout); blocks
// 600..855 = per-block task histogram (plain stores overwrite ws poison) ----
__global__ void prep_count(const void* q1W1, const void* q1W2, const void* q1W3,
                           const void* q2W1, const void* q2W2, const void* q2W3,
                           const void* obs, unsigned short* out,
                           int* hist, unsigned char* tasks){
  __shared__ int sflag;
  int tid = threadIdx.x;
  int isbf16 = block_sniff(obs, tid, &sflag);
  if (blockIdx.x >= 600) {             // ---- count role ----
    __shared__ int h[3];
    if (tid < 3) h[tid] = 0;
    __syncthreads();
    int blk = blockIdx.x - 600;
    int b = blk * 256 + tid;
    int t = task_of(obs, b, isbf16);
    tasks[b] = (unsigned char)t;
    atomicAdd(&h[t], 1);
    __syncthreads();
    if (tid < 3) hist[blk * 3 + tid] = h[tid];
    return;
  }
  // ---- prep role: thread writes 8 consecutive swizzled shorts ----
  int gid8 = (blockIdx.x * 256 + tid) * 8;
  int net = gid8 / 614400;
  int idx = gid8 - net * 614400;
  const void* W1 = net ? q2W1 : q1W1;
  const void* W2 = net ? q2W2 : q1W2;
  const void* W3 = net ? q2W3 : q1W3;
  short8 sv;
  if (idx < 221184) {                  // W1t: KC=9, per task 16*9*512=73728
    int t = idx / 73728; int i = idx - t * 73728;
    int g = i / 4608;  int r = i - g * 4608;
    int kb = r >> 9;   int q2 = r & 511;
    int l16 = q2 >> 5; int rem = q2 & 31;
    int n = g * 16 + l16;
    int k = kb * 32 + (rem & ~7);
    #pragma unroll
    for (int j = 0; j < 8; j++) {
      int kk = k + j;
      sv[j] = (kk < 264) ? (short)f2bf(ldval(W1, (t * 264 + kk) * 256 + n, isbf16)) : (short)0;
    }
  } else if (idx < 417792) {           // W2t: KC=8, per task 16*8*512=65536
    int j0 = idx - 221184;
    int t = j0 >> 16; int i = j0 & 65535;
    int g = i >> 12;  int r = i & 4095;
    int kb = r >> 9;  int q2 = r & 511;
    int l16 = q2 >> 5; int rem = q2 & 31;
    int n = g * 16 + l16;
    int k = kb * 32 + (rem & ~7);
    #pragma unroll
    for (int j = 0; j < 8; j++)
      sv[j] = (short)f2bf(ldval(W2, t * 65536 + (k + j) * 256 + n, isbf16));
  } else {                             // W3t
    int j0 = idx - 417792;
    int t = j0 >> 16; int i = j0 & 65535;
    int g = i >> 12;  int r = i & 4095;
    int kb = r >> 9;  int q2 = r & 511;
    int l16 = q2 >> 5; int rem = q2 & 31;
    int n = g * 16 + l16;
    int k = kb * 32 + (rem & ~7);
    #pragma unroll
    for (int j = 0; j < 8; j++)
      sv[j] = (short)f2bf(ldval(W3, t * 65536 + (k + j) * 256 + n, isbf16));
  }
  *(short8*)(out + net * 614400 + idx) = sv;
}

// ---- K2: scatter, atomic-free cross-block prefix from hists ----
__global__ void route_scatter(const unsigned char* __restrict__ tasks,
                              const int* __restrict__ hist,
                              int* counts, int* perm){
  __shared__ int sh[3][256];
  __shared__ int totals[3], pres[3], base[3], zz[3];
  int tid = threadIdx.x;
  int blk = blockIdx.x;
  sh[0][tid] = hist[tid * 3 + 0];
  sh[1][tid] = hist[tid * 3 + 1];
  sh[2][tid] = hist[tid * 3 + 2];
  if (tid < 3) zz[tid] = 0;
  __syncthreads();
  if (tid < 3) {
    int tot = 0, pre = 0;
    for (int b = 0; b < 256; b++) {
      int v = sh[tid][b];
      if (b < blk) pre += v;
      tot += v;
    }
    totals[tid] = tot; pres[tid] = pre;
  }
  __syncthreads();
  if (tid < 3) {
    int a0 = ((totals[0] + MROWS - 1) / MROWS) * MROWS;
    int a1 = ((totals[1] + MROWS - 1) / MROWS) * MROWS;
    int off = (tid == 0) ? 0 : (tid == 1) ? a0 : a0 + a1;
    base[tid] = off + pres[tid];
    if (blk == 0) counts[tid] = totals[tid];
  }
  __syncthreads();
  int b = blk * 256 + tid;
  int t = tasks[b];
  int r = atomicAdd(&zz[t], 1);
  perm[base[t] + r] = b;
}

// ---- one layer: template-unrolled K, per-wave 48 rows x 32 cols ----
template<int KC>
__device__ __forceinline__ void run_layer(const unsigned short* __restrict__ lin, int lstride,
                                          const unsigned short* __restrict__ wt,
                                          const void* bias, unsigned short* lout,
                                          int isbf16, int wave, int quad, int l16, int nbase){
  const unsigned short* wg = wt + (wave * 2) * (KC * 512) + l16 * 32 + quad * 8;
  short8 bfr[KC][2];
  #pragma unroll
  for (int kb = 0; kb < KC; ++kb) {
    bfr[kb][0] = *(const short8*)(wg + kb * 512);
    bfr[kb][1] = *(const short8*)(wg + KC * 512 + kb * 512);
  }
  f32x4 acc[3][2] = {};
  #pragma unroll
  for (int kb = 0; kb < KC; ++kb) {
    short8 afr[3];
    int ko = kb * 32 + quad * 8;
    #pragma unroll
    for (int mt = 0; mt < 3; mt++)
      afr[mt] = *(const short8*)(lin + (mt * 16 + l16) * lstride + ko);
    #pragma unroll
    for (int mt = 0; mt < 3; mt++)
      #pragma unroll
      for (int nt = 0; nt < 2; nt++)
        acc[mt][nt] = __builtin_amdgcn_mfma_f32_16x16x32_bf16(afr[mt], bfr[kb][nt], acc[mt][nt], 0, 0, 0);
  }
  float bv[2];
  #pragma unroll
  for (int nt = 0; nt < 2; nt++) bv[nt] = ldval(bias, nbase + nt * 16 + l16, isbf16);
  #pragma unroll
  for (int mt = 0; mt < 3; mt++)
    #pragma unroll
    for (int nt = 0; nt < 2; nt++) {
      f32x4 a = acc[mt][nt];
      #pragma unroll
      for (int r = 0; r < 4; r++) {
        float v = fmaxf(a[r] + bv[nt], 0.f);   // C/D: col=lane&15, row=quad*4+r
        lout[(mt * 16 + quad * 4 + r) * HSTR + nbase + nt * 16 + l16] = f2bf(v);
      }
    }
  __syncthreads();
}

// ---- fused: 48-row task-uniform tile, 512 thr / 8 waves; LDS 53,760B ->
// 3 blocks/CU = 24 waves/CU; wave = 48 rows x 32 cols ----
__global__ __launch_bounds__(512, 6) void fused_kernel(KParams p){
  __shared__ unsigned short X[MROWS * XSTR];   // 28,416 B ; reused as HB after L1
  __shared__ unsigned short HA[MROWS * HSTR];  // 25,344 B  (total 53,760)
  unsigned short* HB = X;
  int* sflag = (int*)HA;                       // aliased: HA unused until L1 epi

  int tid = threadIdx.x;
  int net = blockIdx.y;
  int p0  = blockIdx.x * MROWS;
  int isbf16 = block_sniff(p.obs, tid, sflag);
  int c0 = p.counts[0], c1 = p.counts[1], c2 = p.counts[2];
  int off1 = ((c0 + MROWS - 1) / MROWS) * MROWS;
  int off2 = off1 + ((c1 + MROWS - 1) / MROWS) * MROWS;
  int task  = (p0 >= off2) ? 2 : ((p0 >= off1) ? 1 : 0);
  int segend = (task == 0) ? c0 : (task == 1) ? off1 + c1 : off2 + c2;

  // stage X: 8 threads/row (tids 0..383); validity is arithmetic
  if (tid < MROWS * 8) {
    int srow = tid >> 3, seg = tid & 7;
    int pos = p0 + srow;
    int r = (pos < segend) ? p.perm[pos] : -1;
    #pragma unroll
    for (int j = 0; j < 5; ++j) {
      int c = seg + 8 * j;
      if (c <= 35) {
        short8 sv = {0,0,0,0,0,0,0,0};
        if (r >= 0 && c < 33) {
          if (isbf16) {
            const unsigned short* src = (c < 32) ? ((const unsigned short*)p.obs + r * 256 + c * 8)
                                                 : ((const unsigned short*)p.act + r * 8);
            sv = *(const short8*)src;
          } else {
            const float* src = (c < 32) ? ((const float*)p.obs + r * 256 + c * 8)
                                        : ((const float*)p.act + r * 8);
            f32x4 a = *(const f32x4*)src;
            f32x4 b = *(const f32x4*)(src + 4);
            #pragma unroll
            for (int q = 0; q < 4; q++) { sv[q] = (short)f2bf(a[q]); sv[4 + q] = (short)f2bf(b[q]); }
          }
        }
        *(short8*)(X + srow * XSTR + c * 8) = sv;
      }
    }
  }
  __syncthreads();

  int wave = tid >> 6, lane = tid & 63, quad = lane >> 4, l16 = lane & 15;
  int nbase = wave * 32;   // each of 8 waves owns 32 output cols

  int bsz = isbf16 ? 2 : 4;
  run_layer<9>(X,  XSTR, p.w1t[net] + task * 73728, (const char*)p.b1[net] + task * 256 * bsz, HA, isbf16, wave, quad, l16, nbase);
  run_layer<8>(HA, HSTR, p.w2t[net] + task * 65536, (const char*)p.b2[net] + task * 256 * bsz, HB, isbf16, wave, quad, l16, nbase);
  run_layer<8>(HB, HSTR, p.w3t[net] + task * 65536, (const char*)p.b3[net] + task * 256 * bsz, HA, isbf16, wave, quad, l16, nbase);

  // layer 4: y = h3 . w4 + b4  (8 threads/row, 3-level shuffle)
  if (tid < MROWS * 8) {
    int row = tid >> 3, seg = tid & 7;
    float s = 0.f;
    #pragma unroll
    for (int kk = 0; kk < 32; kk += 8) {
      short8 hv = *(const short8*)(HA + row * HSTR + seg * 32 + kk);
      float wv[8];
      if (isbf16) {
        const unsigned short* w4p = (const unsigned short*)p.w4[net] + task * 256 + seg * 32 + kk;
        short8 t = *(const short8*)w4p;
        #pragma unroll
        for (int j = 0; j < 8; j++) wv[j] = bf2f((unsigned short)t[j]);
      } else {
        const float* w4p = (const float*)p.w4[net] + task * 256 + seg * 32 + kk;
        f32x4 a = *(const f32x4*)w4p;
        f32x4 b = *(const f32x4*)(w4p + 4);
        #pragma unroll
        for (int j = 0; j < 4; j++) { wv[j] = a[j]; wv[4 + j] = b[j]; }
      }
      #pragma unroll
      for (int j = 0; j < 8; j++)
        s += bf2f((unsigned short)hv[j]) * wv[j];
    }
    s += __shfl_xor(s, 1);
    s += __shfl_xor(s, 2);
    s += __shfl_xor(s, 4);
    if (seg == 0) {
      int pos = p0 + row;
      if (pos < segend) {
        int r = p.perm[pos];
        float y = s + ldval(p.b4[net], task, isbf16);
        if (isbf16) ((unsigned short*)p.out)[net * NB + r] = f2bf(y);
        else        ((float*)p.out)[net * NB + r] = y;
      }
    }
  }
}

extern "C" void kernel_launch(void* const* d_in, const int* in_sizes, int n_in,
                              void* d_out, int out_size, void* d_ws, size_t ws_size,
                              hipStream_t stream) {
  char* ws = (char*)d_ws;
  int* counts  = (int*)ws;                                // 3 ints @0 (K2 stores)
  int* hist    = (int*)(ws + 64);                         // 256*3 ints (K1 stores)
  unsigned char* tasks = (unsigned char*)(ws + 3200);     // 65536 B (K1 stores)
  int* perm    = (int*)(ws + 68800);                      // <=65632 ints (K2 stores)
  unsigned short* wts  = (unsigned short*)(ws + 331520);  // 2*614400 bf16 (K1 stores)

  const void* obs = d_in[0];
  const void* act = d_in[1];

  prep_count<<<856, 256, 0, stream>>>(d_in[2], d_in[4], d_in[6],
                                      d_in[10], d_in[12], d_in[14],
                                      obs, wts, hist, tasks);
  route_scatter<<<256, 256, 0, stream>>>(tasks, hist, counts, perm);

  KParams kp;
  kp.obs = obs; kp.act = act;
  for (int q = 0; q < 2; q++) {
    int base = 2 + q * 8;
    kp.b1[q] = d_in[base + 1];
    kp.b2[q] = d_in[base + 3];
    kp.b3[q] = d_in[base + 5];
    kp.w4[q] = d_in[base + 6];
    kp.b4[q] = d_in[base + 7];
    kp.w1t[q] = wts + q * 614400;
    kp.w2t[q] = wts + q * 614400 + 221184;
    kp.w3t[q] = wts + q * 614400 + 417792;
  }
  kp.counts = counts; kp.perm = perm;
  kp.out = d_out;

  // 1368 tiles of 48 rows covers worst-case per-task padding (sum ceil <= 1368)
  fused_kernel<<<dim3(1368, 2), 512, 0, stream>>>(kp);
}